// Round 7
// baseline (222.465 us; speedup 1.0000x reference)
//
#include <hip/hip_runtime.h>
#include <math.h>

typedef __attribute__((ext_vector_type(8)))  short short8;   // 8 bf16 (4 VGPRs)
typedef __attribute__((ext_vector_type(16))) float f32x16;   // 32x32 MFMA acc

constexpr int kD  = 2048;
constexpr int kE  = 64;
constexpr int kM  = 64;          // tokens per block -> 256 blocks -> 1/CU
constexpr int kBK = 64;          // K per staging iteration (2 clusters)
constexpr int kIt = kD / kBK;    // 32

// raw fp32 x staging buffers: [row(64)][slot(16) * 16B] with slot ^= (row&15)
constexpr int kXBuf = 64 * 256;  // 16384 B per buffer, 3 buffers

// p limbs in 32-expert B-fragment order (verified R6, absmax 0.0):
// g_B[plane][eg=e>>5][gc=k>>5][kh=(k>>4)&1][lane=(e&31)|(((k>>3)&1)<<5)][j=k&7]
constexpr int kPlaneU = 2 * 64 * 2 * 64 * 8;  // 131072 ushorts per plane
__device__ unsigned short g_B[3 * kPlaneU];   // 786 KB

#define GLOAD_LDS16(gp, lp)                                                   \
  __builtin_amdgcn_global_load_lds(                                          \
      (const __attribute__((address_space(1))) unsigned int*)(gp),           \
      (__attribute__((address_space(3))) unsigned int*)(lp), 16, 0, 0)

// 3-limb truncated bf16 split: v = h + m + l + O(2^-24 |v|)
__device__ __forceinline__ void split3(float v, unsigned& h, unsigned& m, unsigned& l) {
  unsigned u = __float_as_uint(v);
  h = u & 0xFFFF0000u;
  float r1 = v - __uint_as_float(h);
  m = __float_as_uint(r1) & 0xFFFF0000u;
  float r2 = r1 - __uint_as_float(m);
  l = __float_as_uint(r2);
}

__device__ __forceinline__ void pack2(float e0, float e1,
                                      unsigned& dh, unsigned& dm, unsigned& dl) {
  unsigned h0, m0, l0, h1, m1, l1;
  split3(e0, h0, m0, l0);
  split3(e1, h1, m1, l1);
  dh = (h0 >> 16) | h1;
  dm = (m0 >> 16) | m1;
  dl = (l0 >> 16) | (l1 & 0xFFFF0000u);
}

// 8 consecutive fp32 (two float4) -> 3 limb short8 fragments
__device__ __forceinline__ void mk_frag(float4 va, float4 vb,
                                        short8& Ah, short8& Am, short8& Al) {
  unsigned h0,m0,l0,h1,m1,l1,h2,m2,l2,h3,m3,l3;
  pack2(va.x, va.y, h0, m0, l0);
  pack2(va.z, va.w, h1, m1, l1);
  pack2(vb.x, vb.y, h2, m2, l2);
  pack2(vb.z, vb.w, h3, m3, l3);
  union { unsigned u[4]; short8 s; } U;
  U.u[0]=h0; U.u[1]=h1; U.u[2]=h2; U.u[3]=h3; Ah = U.s;
  U.u[0]=m0; U.u[1]=m1; U.u[2]=m2; U.u[3]=m3; Am = U.s;
  U.u[0]=l0; U.u[1]=l1; U.u[2]=l2; U.u[3]=l3; Al = U.s;
}

// ---------------------------------------------------------------------------
// Prep: unchanged from R6 (verified absmax 0.0).
// ---------------------------------------------------------------------------
__global__ __launch_bounds__(256) void proto_prep(const float* __restrict__ p,
                                                  float* __restrict__ ws) {
  const int e = blockIdx.x, t = threadIdx.x;
  const float* row = p + (size_t)e * kD;
  float4 v0 = *(const float4*)(row + 8 * t);
  float4 v1 = *(const float4*)(row + 8 * t + 4);

  unsigned dh[4], dm[4], dl[4];
  pack2(v0.x, v0.y, dh[0], dm[0], dl[0]);
  pack2(v0.z, v0.w, dh[1], dm[1], dl[1]);
  pack2(v1.x, v1.y, dh[2], dm[2], dl[2]);
  pack2(v1.z, v1.w, dh[3], dm[3], dl[3]);
  const int gc = t >> 2;             // k>>5
  const int kh = (t >> 1) & 1;       // (k>>4)&1
  const int lb = t & 1;              // (k>>3)&1
  size_t base = ((((size_t)(e >> 5) * 64 + gc) * 2 + kh) * 64
                 + ((e & 31) | (lb << 5))) * 8;
  *(uint4*)&g_B[base]               = make_uint4(dh[0], dh[1], dh[2], dh[3]);
  *(uint4*)&g_B[kPlaneU + base]     = make_uint4(dm[0], dm[1], dm[2], dm[3]);
  *(uint4*)&g_B[2 * kPlaneU + base] = make_uint4(dl[0], dl[1], dl[2], dl[3]);

  float s = (v0.x + v0.y) + (v0.z + v0.w) + (v1.x + v1.y) + (v1.z + v1.w);
  float q = v0.x*v0.x + v0.y*v0.y + v0.z*v0.z + v0.w*v0.w
          + v1.x*v1.x + v1.y*v1.y + v1.z*v1.z + v1.w*v1.w;
  #pragma unroll
  for (int off = 32; off >= 1; off >>= 1) {
    s += __shfl_xor(s, off, 64);
    q += __shfl_xor(q, off, 64);
  }
  __shared__ float as[4], aq[4];
  if ((t & 63) == 0) { as[t >> 6] = s; aq[t >> 6] = q; }
  __syncthreads();
  if (t == 0) {
    float S = (as[0] + as[1]) + (as[2] + as[3]);
    float Q = (aq[0] + aq[1]) + (aq[2] + aq[3]);
    ws[e]      = S;
    ws[kE + e] = 1.f / fmaxf(sqrtf(Q), 1e-8f);
  }
}

// ---------------------------------------------------------------------------
// Main: 64 tokens/block, 512 thr (8 waves) = (token-tile tt) x (expert-half
// eg) x (K-parity kp). Raw fp32 x staged async via global_load_lds into 3
// swizzled LDS buffers; ONE raw s_barrier + counted vmcnt per iteration
// (loads never drained to 0 in the loop). Limb conversion in-wave before
// MFMA; dual kh accumulator chains (numerics == R6).
// ---------------------------------------------------------------------------
__global__ __launch_bounds__(512, 2) void router_main(
    const float* __restrict__ x, const float* __restrict__ ws,
    float* __restrict__ out_w, float* __restrict__ out_i) {
  __shared__ __align__(16) unsigned char sA[3 * kXBuf];   // 49152 B

  const int t    = threadIdx.x;     // 0..511
  const int w    = t >> 6;          // wave 0..7
  const int L    = t & 63;
  const int tt   = w >> 2;          // token tile: rows [32tt, 32tt+32)
  const int eg   = (w >> 1) & 1;    // experts [32eg, 32eg+32)
  const int kp   = w & 1;           // K parity: cluster g = 2it + kp
  const int tok0 = blockIdx.x * kM;
  const float* xg = x + (size_t)tok0 * kD;

  // ---- async stage of iteration its into buffer bufI (2 issues per wave)
  auto stageIt = [&](int its, int bufI) {
    unsigned char* base = sA + bufI * kXBuf;
    const int kbase = its * kBK;
    #pragma unroll
    for (int qq = 0; qq < 2; ++qq) {
      const int r0  = w * 8 + qq * 4;
      const int row = r0 + (L >> 4);
      const int slot = (L & 15) ^ (row & 15);       // pre-swizzled source
      const float* gp = xg + (size_t)row * kD + kbase + slot * 4;
      unsigned char* lp = base + r0 * 256 + L * 16; // linear dest
      GLOAD_LDS16(gp, lp);
    }
  };

  // B fragment address for global cluster g, k-half kh
  auto bIdx = [&](int g, int kh) -> size_t {
    return ((((size_t)eg * 64 + g) * 2 + kh) * 64 + L) * 8;
  };

  f32x16 accA, accB;
  #pragma unroll
  for (int i = 0; i < 16; ++i) { accA[i] = 0.f; accB[i] = 0.f; }
  float sx = 0.f, sxx = 0.f;

  // ---- prologue: stage it 0,1; load B(cluster kp)
  stageIt(0, 0);
  stageIt(1, 1);
  short8 BcH0, BcM0, BcL0, BcH1, BcM1, BcL1;
  {
    size_t b0 = bIdx(kp, 0), b1 = bIdx(kp, 1);
    BcH0 = *(const short8*)&g_B[b0];
    BcM0 = *(const short8*)&g_B[kPlaneU + b0];
    BcL0 = *(const short8*)&g_B[2 * kPlaneU + b0];
    BcH1 = *(const short8*)&g_B[b1];
    BcM1 = *(const short8*)&g_B[kPlaneU + b1];
    BcL1 = *(const short8*)&g_B[2 * kPlaneU + b1];
  }

  const int aRow  = tt * 32 + (L & 31);
  const unsigned char* rRow0 = sA + aRow * 256;
  const int sw    = aRow & 15;
  const int sBase = kp * 8 + 2 * (L >> 5);   // + kh*4, 16B-slot units

  for (int it = 0; it < kIt; ++it) {
    // P1: B prefetch for it+1
    short8 BnH0 = BcH0, BnM0 = BcM0, BnL0 = BcL0;
    short8 BnH1 = BcH1, BnM1 = BcM1, BnL1 = BcL1;
    if (it + 1 < kIt) {
      const int g1 = 2 * (it + 1) + kp;
      size_t b0 = bIdx(g1, 0), b1 = bIdx(g1, 1);
      BnH0 = *(const short8*)&g_B[b0];
      BnM0 = *(const short8*)&g_B[kPlaneU + b0];
      BnL0 = *(const short8*)&g_B[2 * kPlaneU + b0];
      BnH1 = *(const short8*)&g_B[b1];
      BnM1 = *(const short8*)&g_B[kPlaneU + b1];
      BnL1 = *(const short8*)&g_B[2 * kPlaneU + b1];
    }

    // P2: counted wait — drain own stage(it) issues, keep the rest in flight.
    // queue (oldest->newest): stage(it):2, B(it):6, stage(it+1):2, B(it+1):6
    if (it + 1 < kIt) asm volatile("s_waitcnt vmcnt(14)" ::: "memory");
    else              asm volatile("s_waitcnt vmcnt(6)"  ::: "memory");
    __builtin_amdgcn_sched_barrier(0);

    // P3: all waves drained their own slice -> buf[it%3] complete
    __builtin_amdgcn_s_barrier();
    __builtin_amdgcn_sched_barrier(0);

    // P4: stage it+2 into buf[(it+2)%3] (its readers finished at it-1)
    if (it + 2 < kIt) stageIt(it + 2, (it + 2) % 3);

    // P5: read fp32, convert to limbs, 12 MFMAs (2 kh chains)
    const unsigned char* rb = rRow0 + (it % 3) * kXBuf;
    float4 va0 = *(const float4*)(rb + (((sBase    )     ) ^ sw) * 16);
    float4 vb0 = *(const float4*)(rb + (((sBase    ) + 1 ) ^ sw) * 16);
    float4 va1 = *(const float4*)(rb + (((sBase + 4)     ) ^ sw) * 16);
    float4 vb1 = *(const float4*)(rb + (((sBase + 4) + 1 ) ^ sw) * 16);

    if (eg == 0) {   // LN stats: each element counted once across eg0 waves
      sx  += ((va0.x + va0.y) + (va0.z + va0.w)) + ((vb0.x + vb0.y) + (vb0.z + vb0.w))
           + ((va1.x + va1.y) + (va1.z + va1.w)) + ((vb1.x + vb1.y) + (vb1.z + vb1.w));
      float q0 = fmaf(va0.x,va0.x, fmaf(va0.y,va0.y, fmaf(va0.z,va0.z, va0.w*va0.w)));
      float q1 = fmaf(vb0.x,vb0.x, fmaf(vb0.y,vb0.y, fmaf(vb0.z,vb0.z, vb0.w*vb0.w)));
      float q2 = fmaf(va1.x,va1.x, fmaf(va1.y,va1.y, fmaf(va1.z,va1.z, va1.w*va1.w)));
      float q3 = fmaf(vb1.x,vb1.x, fmaf(vb1.y,vb1.y, fmaf(vb1.z,vb1.z, vb1.w*vb1.w)));
      sxx += (q0 + q1) + (q2 + q3);
    }

    short8 Ah0, Am0, Al0, Ah1, Am1, Al1;
    mk_frag(va0, vb0, Ah0, Am0, Al0);
    mk_frag(va1, vb1, Ah1, Am1, Al1);

    __builtin_amdgcn_s_setprio(1);
    accA = __builtin_amdgcn_mfma_f32_32x32x16_bf16(Ah0, BcH0, accA, 0, 0, 0);
    accB = __builtin_amdgcn_mfma_f32_32x32x16_bf16(Ah1, BcH1, accB, 0, 0, 0);
    accA = __builtin_amdgcn_mfma_f32_32x32x16_bf16(Ah0, BcM0, accA, 0, 0, 0);
    accB = __builtin_amdgcn_mfma_f32_32x32x16_bf16(Ah1, BcM1, accB, 0, 0, 0);
    accA = __builtin_amdgcn_mfma_f32_32x32x16_bf16(Am0, BcH0, accA, 0, 0, 0);
    accB = __builtin_amdgcn_mfma_f32_32x32x16_bf16(Am1, BcH1, accB, 0, 0, 0);
    accA = __builtin_amdgcn_mfma_f32_32x32x16_bf16(Am0, BcM0, accA, 0, 0, 0);
    accB = __builtin_amdgcn_mfma_f32_32x32x16_bf16(Am1, BcM1, accB, 0, 0, 0);
    accA = __builtin_amdgcn_mfma_f32_32x32x16_bf16(Ah0, BcL0, accA, 0, 0, 0);
    accB = __builtin_amdgcn_mfma_f32_32x32x16_bf16(Ah1, BcL1, accB, 0, 0, 0);
    accA = __builtin_amdgcn_mfma_f32_32x32x16_bf16(Al0, BcH0, accA, 0, 0, 0);
    accB = __builtin_amdgcn_mfma_f32_32x32x16_bf16(Al1, BcH1, accB, 0, 0, 0);
    __builtin_amdgcn_s_setprio(0);

    BcH0 = BnH0; BcM0 = BnM0; BcL0 = BnL0;
    BcH1 = BnH1; BcM1 = BnM1; BcL1 = BnL1;
  }

  __syncthreads();   // full drain once; x-buffers now reusable

  // overlay epilogue scratch onto the x staging area
  float* sLogit  = (float*)sA;                     // [64][68]  17408 B
  float* sStatsP = (float*)(sA + kM * 68 * 4);     // [2][64][2] 1024 B

  // LN stats: lanes l and l^32 of each eg0 wave cover disjoint k of token l&31
  if (eg == 0) {
    float a = sx  + __shfl_xor(sx, 32, 64);
    float b = sxx + __shfl_xor(sxx, 32, 64);
    if (L < 32) {
      int m = tt * 32 + L;
      sStatsP[(kp * kM + m) * 2 + 0] = a;
      sStatsP[(kp * kM + m) * 2 + 1] = b;
    }
  }

  // partial dots: kp0 stores, kp1 adds  (C layout verified R6)
  if (kp == 0) {
    #pragma unroll
    for (int i = 0; i < 16; ++i) {
      int row = (i & 3) + 8 * (i >> 2) + 4 * (L >> 5);
      sLogit[(tt * 32 + row) * 68 + eg * 32 + (L & 31)] = accA[i] + accB[i];
    }
  }
  __syncthreads();
  if (kp == 1) {
    #pragma unroll
    for (int i = 0; i < 16; ++i) {
      int row = (i & 3) + 8 * (i >> 2) + 4 * (L >> 5);
      sLogit[(tt * 32 + row) * 68 + eg * 32 + (L & 31)] += accA[i] + accB[i];
    }
  }
  __syncthreads();

  // epilogue: wave w -> tokens [8w, 8w+8), lane = expert
  const float Se  = ws[L];
  const float inv = ws[kE + L];
  #pragma unroll
  for (int tl = 0; tl < 8; ++tl) {
    int tk = w * 8 + tl;
    float st0 = sStatsP[tk * 2 + 0] + sStatsP[(kM + tk) * 2 + 0];
    float st1 = sStatsP[tk * 2 + 1] + sStatsP[(kM + tk) * 2 + 1];
    float mu   = st0 * (1.f / kD);
    float var  = st1 * (1.f / kD) - mu * mu;
    float rstd = rsqrtf(var + 1e-5f);
    float logit = (sLogit[tk * 68 + L] - mu * Se) * rstd * inv * 0.125f;

    float v1 = logit; int i1 = L;
    #pragma unroll
    for (int off = 32; off >= 1; off >>= 1) {
      float ov = __shfl_xor(v1, off, 64);
      int   oi = __shfl_xor(i1, off, 64);
      if (ov > v1 || (ov == v1 && oi < i1)) { v1 = ov; i1 = oi; }
    }
    float ml = (L == i1) ? -3.402823466e38f : logit;
    float v2 = ml; int i2 = L;
    #pragma unroll
    for (int off = 32; off >= 1; off >>= 1) {
      float ov = __shfl_xor(v2, off, 64);
      int   oi = __shfl_xor(i2, off, 64);
      if (ov > v2 || (ov == v2 && oi < i2)) { v2 = ov; i2 = oi; }
    }
    if (L == 0) {
      int tg = tok0 + tk;
      float er = expf(v2 - v1);
      float r  = 1.f / (1.f + er);
      out_w[2 * tg]     = r;
      out_w[2 * tg + 1] = er * r;
      out_i[2 * tg]     = (float)i1;   // harness reads whole buffer as f32
      out_i[2 * tg + 1] = (float)i2;
    }
  }
}

extern "C" void kernel_launch(void* const* d_in, const int* in_sizes, int n_in,
                              void* d_out, int out_size, void* d_ws, size_t ws_size,
                              hipStream_t stream) {
  const float* x = (const float*)d_in[0];   // [4,4096,2048] fp32
  const float* p = (const float*)d_in[1];   // [64,2048] fp32
  float* ws = (float*)d_ws;                 // 128 floats
  const int T = in_sizes[0] / kD;           // 16384 tokens
  float* out_w = (float*)d_out;
  float* out_i = (float*)d_out + (size_t)T * 2;

  proto_prep<<<kE, 256, 0, stream>>>(p, ws);
  router_main<<<T / kM, 512, 0, stream>>>(x, ws, out_w, out_i);
}